// Round 8
// baseline (901.474 us; speedup 1.0000x reference)
//
#include <hip/hip_runtime.h>

#define N_NODES 100000
#define N_EDGES 1600000
#define HID 128
#define N_LAYERS 4
#define EPSV 1e-5f
#define SCAN_BLK 98  // ceil(100000/1024)
#define ASTR 136     // A-tile LDS row stride in shorts (272B; 16B-aligned; b128 reads hit the 8/bank floor)

using f32x4 = __attribute__((ext_vector_type(4))) float;
using s16x8 = __attribute__((ext_vector_type(8))) short;

__device__ __forceinline__ unsigned short f2bf(float f) {
  union { float f; unsigned u; } c{f};
  unsigned u = c.u;
  return (unsigned short)((u + 0x7fffu + ((u >> 16) & 1u)) >> 16);
}
__device__ __forceinline__ float bf2f(unsigned short s) {
  union { unsigned u; float f; } c{(unsigned)s << 16};
  return c.f;
}

// ---------------- deg_in only (deg_out fused into fill_csr) ----------------
__global__ __launch_bounds__(256) void k_deg_in(const int* __restrict__ dst, int* __restrict__ deg_in) {
  int i = blockIdx.x * 256 + threadIdx.x;
  if (i < N_EDGES) atomicAdd(&deg_in[dst[i]], 1);
}

__global__ __launch_bounds__(256) void k_norms(const int* __restrict__ deg_out, const int* __restrict__ deg_in,
                                               float* __restrict__ norm_src, float* __restrict__ norm_dst) {
  int i = blockIdx.x * 256 + threadIdx.x;
  if (i < N_NODES) {
    int d_o = deg_out[i], d_i = deg_in[i];
    norm_src[i] = d_o > 0 ? rsqrtf((float)d_o) : 0.f;
    norm_dst[i] = d_i > 0 ? rsqrtf((float)d_i) : 0.f;
  }
}

// ---------------- 3-kernel exclusive scan ----------------
__global__ __launch_bounds__(256) void k_scan1(const int* __restrict__ in, int* __restrict__ out,
                                               int* __restrict__ partials) {
  __shared__ int wsum[4];
  int tid = threadIdx.x;
  int base = blockIdx.x * 1024 + tid * 4;
  int4 v = {0, 0, 0, 0};
  if (base + 3 < N_NODES) v = *(const int4*)(in + base);
  else {
    if (base + 0 < N_NODES) v.x = in[base + 0];
    if (base + 1 < N_NODES) v.y = in[base + 1];
    if (base + 2 < N_NODES) v.z = in[base + 2];
    if (base + 3 < N_NODES) v.w = in[base + 3];
  }
  int s4 = v.x + v.y + v.z + v.w;
  int lane = tid & 63, wid = tid >> 6;
  int sc = s4;
#pragma unroll
  for (int off = 1; off < 64; off <<= 1) {
    int u = __shfl_up(sc, off, 64);
    if (lane >= off) sc += u;
  }
  if (lane == 63) wsum[wid] = sc;
  __syncthreads();
  int woff = 0;
#pragma unroll
  for (int w = 0; w < 4; ++w) woff += (w < wid) ? wsum[w] : 0;
  int excl = woff + sc - s4;
  int4 o;
  o.x = excl; o.y = o.x + v.x; o.z = o.y + v.y; o.w = o.z + v.z;
  if (base + 3 < N_NODES) *(int4*)(out + base) = o;
  else {
    if (base + 0 < N_NODES) out[base + 0] = o.x;
    if (base + 1 < N_NODES) out[base + 1] = o.y;
    if (base + 2 < N_NODES) out[base + 2] = o.z;
    if (base + 3 < N_NODES) out[base + 3] = o.w;
  }
  if (tid == 255) partials[blockIdx.x] = woff + sc;
}

__global__ __launch_bounds__(128) void k_scan2(const int* __restrict__ partials, int* __restrict__ poff,
                                               int* __restrict__ row_ptr) {
  __shared__ int w0s;
  int tid = threadIdx.x;
  int v = (tid < SCAN_BLK) ? partials[tid] : 0;
  int sc = v;
#pragma unroll
  for (int off = 1; off < 64; off <<= 1) {
    int u = __shfl_up(sc, off, 64);
    if ((tid & 63) >= off) sc += u;
  }
  if (tid == 63) w0s = sc;
  __syncthreads();
  int incl = sc + ((tid >= 64) ? w0s : 0);
  if (tid < SCAN_BLK) poff[tid] = incl - v;
  if (tid == 127) row_ptr[N_NODES] = incl;
}

__global__ __launch_bounds__(256) void k_scan3(int* __restrict__ row_ptr, const int* __restrict__ poff,
                                               int* __restrict__ cursor) {
  int tid = threadIdx.x;
  int base = blockIdx.x * 1024 + tid * 4;
  int p = poff[blockIdx.x];
  if (base + 3 < N_NODES) {
    int4 v = *(int4*)(row_ptr + base);
    v.x += p; v.y += p; v.z += p; v.w += p;
    *(int4*)(row_ptr + base) = v;
    *(int4*)(cursor + base) = v;
  } else {
    for (int k = 0; k < 4; ++k)
      if (base + k < N_NODES) {
        int t = row_ptr[base + k] + p;
        row_ptr[base + k] = t;
        cursor[base + k] = t;
      }
  }
}

// ---------------- CSR fill + deg_out histogram ----------------
__global__ __launch_bounds__(256) void k_fill_csr(const int* __restrict__ src, const int* __restrict__ dst,
                                                  int* __restrict__ cursor, int* __restrict__ csr_src,
                                                  int* __restrict__ deg_out) {
  int i = blockIdx.x * 256 + threadIdx.x;
  if (i < N_EDGES) {
    int s = src[i];
    atomicAdd(&deg_out[s], 1);
    int d = dst[i];
    int pos = atomicAdd(&cursor[d], 1);
    csr_src[pos] = s;
  }
}

// ---------------- embedding lookup: writes x (fp32) + xb (bf16, prescaled by norm_src) ----------------
__global__ __launch_bounds__(256) void k_embed(const int* __restrict__ h, const float* __restrict__ emb,
                                               const float* __restrict__ norm_src,
                                               float* __restrict__ x, unsigned short* __restrict__ xb) {
  int i = blockIdx.x * 256 + threadIdx.x;  // over N*32 float4
  const int total = N_NODES * (HID / 4);
  if (i < total) {
    int r = i >> 5, c = i & 31;
    float4 v = ((const float4*)emb)[h[r] * (HID / 4) + c];
    ((float4*)x)[i] = v;
    float ns = norm_src[r];
    uint2 p;
    p.x = (unsigned)f2bf(v.x * ns) | ((unsigned)f2bf(v.y * ns) << 16);
    p.y = (unsigned)f2bf(v.z * ns) | ((unsigned)f2bf(v.w * ns) << 16);
    *(uint2*)(xb + (size_t)i * 4) = p;
  }
}

// ---------------- W split+transpose: Wt[l][col][k] hi/lo bf16 ----------------
__global__ __launch_bounds__(128) void k_wsplit(const float* __restrict__ W, unsigned short* __restrict__ Wh,
                                                unsigned short* __restrict__ Wl) {
  int l = blockIdx.x >> 7, k = blockIdx.x & 127;
  int c = threadIdx.x;
  float w = W[(size_t)l * HID * HID + k * HID + c];
  unsigned short h = f2bf(w);
  Wh[(size_t)l * HID * HID + c * HID + k] = h;
  Wl[(size_t)l * HID * HID + c * HID + k] = f2bf(w - bf2f(h));
}

// ---------------- FUSED aggregation + MFMA GEMM + BN stats ----------------
// Phase 1: block gathers its 128-row A-tile (prescaled bf16 xb, fp32 accum, *norm_dst),
//          splits hi/lo bf16 straight into LDS (full K resident, 70 KB, 2 blocks/CU).
// Phase 2: barrier-free kb loop; A fragments from LDS, B fragments direct from global (L2-hot).
// Phase 3: bias + Y store + fused BN column stats.
__global__ __launch_bounds__(256, 2) void k_agg_gemm(const unsigned short* __restrict__ xb,
                                                     const int* __restrict__ row_ptr,
                                                     const int* __restrict__ csr_src,
                                                     const float* __restrict__ norm_dst,
                                                     const unsigned short* __restrict__ Bh,
                                                     const unsigned short* __restrict__ Bl,
                                                     const float* __restrict__ bias, float* __restrict__ Y,
                                                     float* __restrict__ sums, float* __restrict__ sumsq) {
  __shared__ unsigned short sAh[128 * ASTR], sAl[128 * ASTR];  // 69632 B
  const int tid = threadIdx.x;
  const int lane = tid & 63, wid = tid >> 6;
  const int l15 = lane & 15, kg = lane >> 4;
  const int row0 = blockIdx.x * 128;
  const int grp = tid >> 4, l16 = tid & 15;

  // ---- Phase 1: gather ----
#pragma unroll 1
  for (int it = 0; it < 8; ++it) {
    int r = it * 16 + grp;
    int node = row0 + r;
    float acc[8];
#pragma unroll
    for (int j = 0; j < 8; ++j) acc[j] = 0.f;
    float nd = 0.f;
    if (node < N_NODES) {
      int s0 = row_ptr[node], s1 = row_ptr[node + 1];
      int i = s0;
      for (; i + 7 < s1; i += 8) {
        uint4 u0 = *(const uint4*)(xb + (size_t)csr_src[i + 0] * HID + l16 * 8);
        uint4 u1 = *(const uint4*)(xb + (size_t)csr_src[i + 1] * HID + l16 * 8);
        uint4 u2 = *(const uint4*)(xb + (size_t)csr_src[i + 2] * HID + l16 * 8);
        uint4 u3 = *(const uint4*)(xb + (size_t)csr_src[i + 3] * HID + l16 * 8);
        uint4 u4 = *(const uint4*)(xb + (size_t)csr_src[i + 4] * HID + l16 * 8);
        uint4 u5 = *(const uint4*)(xb + (size_t)csr_src[i + 5] * HID + l16 * 8);
        uint4 u6 = *(const uint4*)(xb + (size_t)csr_src[i + 6] * HID + l16 * 8);
        uint4 u7 = *(const uint4*)(xb + (size_t)csr_src[i + 7] * HID + l16 * 8);
        unsigned ue[8][4] = {{u0.x, u0.y, u0.z, u0.w}, {u1.x, u1.y, u1.z, u1.w},
                             {u2.x, u2.y, u2.z, u2.w}, {u3.x, u3.y, u3.z, u3.w},
                             {u4.x, u4.y, u4.z, u4.w}, {u5.x, u5.y, u5.z, u5.w},
                             {u6.x, u6.y, u6.z, u6.w}, {u7.x, u7.y, u7.z, u7.w}};
#pragma unroll
        for (int e = 0; e < 8; ++e)
#pragma unroll
          for (int q = 0; q < 4; ++q) {
            union { unsigned u; float f; } lo{ue[e][q] << 16}, hi{ue[e][q] & 0xffff0000u};
            acc[q * 2 + 0] += lo.f;
            acc[q * 2 + 1] += hi.f;
          }
      }
      for (; i + 3 < s1; i += 4) {
        uint4 u0 = *(const uint4*)(xb + (size_t)csr_src[i + 0] * HID + l16 * 8);
        uint4 u1 = *(const uint4*)(xb + (size_t)csr_src[i + 1] * HID + l16 * 8);
        uint4 u2 = *(const uint4*)(xb + (size_t)csr_src[i + 2] * HID + l16 * 8);
        uint4 u3 = *(const uint4*)(xb + (size_t)csr_src[i + 3] * HID + l16 * 8);
        unsigned ue[4][4] = {{u0.x, u0.y, u0.z, u0.w}, {u1.x, u1.y, u1.z, u1.w},
                             {u2.x, u2.y, u2.z, u2.w}, {u3.x, u3.y, u3.z, u3.w}};
#pragma unroll
        for (int e = 0; e < 4; ++e)
#pragma unroll
          for (int q = 0; q < 4; ++q) {
            union { unsigned u; float f; } lo{ue[e][q] << 16}, hi{ue[e][q] & 0xffff0000u};
            acc[q * 2 + 0] += lo.f;
            acc[q * 2 + 1] += hi.f;
          }
      }
      for (; i < s1; ++i) {
        uint4 u = *(const uint4*)(xb + (size_t)csr_src[i] * HID + l16 * 8);
        unsigned uu[4] = {u.x, u.y, u.z, u.w};
#pragma unroll
        for (int q = 0; q < 4; ++q) {
          union { unsigned u; float f; } lo{uu[q] << 16}, hi{uu[q] & 0xffff0000u};
          acc[q * 2 + 0] += lo.f;
          acc[q * 2 + 1] += hi.f;
        }
      }
      nd = norm_dst[node];
    }
    short hh[8], ll[8];
#pragma unroll
    for (int j = 0; j < 8; ++j) {
      float v = acc[j] * nd;
      unsigned short hb = f2bf(v);
      hh[j] = (short)hb;
      ll[j] = (short)f2bf(v - bf2f(hb));
    }
    *(s16x8*)&sAh[r * ASTR + l16 * 8] = (s16x8){hh[0], hh[1], hh[2], hh[3], hh[4], hh[5], hh[6], hh[7]};
    *(s16x8*)&sAl[r * ASTR + l16 * 8] = (s16x8){ll[0], ll[1], ll[2], ll[3], ll[4], ll[5], ll[6], ll[7]};
  }
  __syncthreads();

  // ---- Phase 2: barrier-free MFMA K loop ----
  f32x4 acc[2][8];
#pragma unroll
  for (int mi = 0; mi < 2; ++mi)
#pragma unroll
    for (int ni = 0; ni < 8; ++ni) acc[mi][ni] = (f32x4){0.f, 0.f, 0.f, 0.f};

#pragma unroll
  for (int kb = 0; kb < 4; ++kb) {
    const int k0 = kb * 32;
    s16x8 afh[2], afl[2];
#pragma unroll
    for (int mi = 0; mi < 2; ++mi) {
      int ar = wid * 32 + mi * 16 + l15;
      afh[mi] = *(const s16x8*)&sAh[ar * ASTR + k0 + kg * 8];
      afl[mi] = *(const s16x8*)&sAl[ar * ASTR + k0 + kg * 8];
    }
#pragma unroll
    for (int ni = 0; ni < 8; ++ni) {
      int bc = ni * 16 + l15;
      s16x8 bh = *(const s16x8*)(Bh + (size_t)bc * HID + k0 + kg * 8);
      s16x8 bl = *(const s16x8*)(Bl + (size_t)bc * HID + k0 + kg * 8);
#pragma unroll
      for (int mi = 0; mi < 2; ++mi) {
        acc[mi][ni] = __builtin_amdgcn_mfma_f32_16x16x32_bf16(afh[mi], bh, acc[mi][ni], 0, 0, 0);
        acc[mi][ni] = __builtin_amdgcn_mfma_f32_16x16x32_bf16(afh[mi], bl, acc[mi][ni], 0, 0, 0);
        acc[mi][ni] = __builtin_amdgcn_mfma_f32_16x16x32_bf16(afl[mi], bh, acc[mi][ni], 0, 0, 0);
      }
    }
  }

  // ---- Phase 3: bias + store + BN stats ----
  float bv[8], sp[8], qp[8];
#pragma unroll
  for (int ni = 0; ni < 8; ++ni) {
    bv[ni] = bias[ni * 16 + l15];
    sp[ni] = 0.f; qp[ni] = 0.f;
  }
#pragma unroll
  for (int mi = 0; mi < 2; ++mi) {
    int rbase = row0 + wid * 32 + mi * 16 + kg * 4;
#pragma unroll
    for (int reg = 0; reg < 4; ++reg) {
      int r = rbase + reg;
      if (r < N_NODES) {
        float* yr = Y + (size_t)r * HID;
#pragma unroll
        for (int ni = 0; ni < 8; ++ni) {
          float y = acc[mi][ni][reg] + bv[ni];
          yr[ni * 16 + l15] = y;
          sp[ni] += y;
          qp[ni] += y * y;
        }
      }
    }
  }
  __syncthreads();
  float* red_s = (float*)sAh;  // [16][128] = 8KB
  float* red_q = (float*)sAl;
  int slot = wid * 4 + kg;
#pragma unroll
  for (int ni = 0; ni < 8; ++ni) {
    red_s[slot * 128 + ni * 16 + l15] = sp[ni];
    red_q[slot * 128 + ni * 16 + l15] = qp[ni];
  }
  __syncthreads();
  if (tid < 128) {
    float a = 0.f, b2 = 0.f;
#pragma unroll
    for (int s = 0; s < 16; ++s) {
      a += red_s[s * 128 + tid];
      b2 += red_q[s * 128 + tid];
    }
    atomicAdd(&sums[tid], a);
    atomicAdd(&sumsq[tid], b2);
  }
}

// ---------------- BN finalize ----------------
__global__ __launch_bounds__(128) void k_bn_final(const float* __restrict__ sums, const float* __restrict__ sumsq,
                                                  const float* __restrict__ gamma, const float* __restrict__ beta,
                                                  float* __restrict__ scale, float* __restrict__ shift) {
  int d = threadIdx.x;
  float mu = sums[d] / (float)N_NODES;
  float var = sumsq[d] / (float)N_NODES - mu * mu;
  float sc = gamma[d] * rsqrtf(var + EPSV);
  scale[d] = sc;
  shift[d] = beta[d] - mu * sc;
}

// ---------------- BN apply + relu + residual; writes x (fp32) + xb (bf16, prescaled) ----------------
__global__ __launch_bounds__(256) void k_bn_apply(const float* __restrict__ Y, const float* __restrict__ scale,
                                                  const float* __restrict__ shift, const float* __restrict__ norm_src,
                                                  float* __restrict__ x, unsigned short* __restrict__ xb) {
  int i = blockIdx.x * 256 + threadIdx.x;
  const int total = N_NODES * (HID / 4);
  if (i >= total) return;
  int c4 = i & 31, r = i >> 5;
  float4 y = ((const float4*)Y)[i];
  float4 sc = ((const float4*)scale)[c4];
  float4 sh = ((const float4*)shift)[c4];
  float4 xv = ((const float4*)x)[i];
  float4 o;
  o.x = fmaxf(y.x * sc.x + sh.x, 0.f) + xv.x;
  o.y = fmaxf(y.y * sc.y + sh.y, 0.f) + xv.y;
  o.z = fmaxf(y.z * sc.z + sh.z, 0.f) + xv.z;
  o.w = fmaxf(y.w * sc.w + sh.w, 0.f) + xv.w;
  ((float4*)x)[i] = o;
  float ns = norm_src[r];
  uint2 p;
  p.x = (unsigned)f2bf(o.x * ns) | ((unsigned)f2bf(o.y * ns) << 16);
  p.y = (unsigned)f2bf(o.z * ns) | ((unsigned)f2bf(o.w * ns) << 16);
  *(uint2*)(xb + (size_t)i * 4) = p;
}

// ---------------- fused layer-4 BN + MLP readout: reads Yb + x, writes out only ----------------
__global__ __launch_bounds__(256) void k_mlp_bn_fused(const float* __restrict__ Yb, const float* __restrict__ Xres,
                                                      const float* __restrict__ scale, const float* __restrict__ shift,
                                                      const float* __restrict__ W1, const float* __restrict__ b1,
                                                      const float* __restrict__ W2, const float* __restrict__ b2,
                                                      const float* __restrict__ W3, const float* __restrict__ b3,
                                                      float* __restrict__ out) {
  __shared__ float Ws1[128 * 64];
  __shared__ float Ws2[64 * 32];
  __shared__ float Ws3[32 * 6];
  __shared__ float bs1[64], bs2[32], bs3[6];
  __shared__ float scs[128], shs[128];
  for (int i = threadIdx.x; i < 128 * 64; i += 256) Ws1[i] = W1[i];
  for (int i = threadIdx.x; i < 64 * 32; i += 256) Ws2[i] = W2[i];
  for (int i = threadIdx.x; i < 32 * 6; i += 256) Ws3[i] = W3[i];
  if (threadIdx.x < 64) bs1[threadIdx.x] = b1[threadIdx.x];
  else if (threadIdx.x < 96) bs2[threadIdx.x - 64] = b2[threadIdx.x - 64];
  else if (threadIdx.x < 102) bs3[threadIdx.x - 96] = b3[threadIdx.x - 96];
  if (threadIdx.x < 128) { scs[threadIdx.x] = scale[threadIdx.x]; shs[threadIdx.x] = shift[threadIdx.x]; }
  __syncthreads();
  int r = blockIdx.x * 256 + threadIdx.x;
  if (r >= N_NODES) return;
  const float4* yr = (const float4*)(Yb + (size_t)r * 128);
  const float4* xr = (const float4*)(Xres + (size_t)r * 128);
  float h1[64];
#pragma unroll
  for (int c = 0; c < 64; ++c) h1[c] = bs1[c];
  for (int k4 = 0; k4 < 32; ++k4) {
    float4 yv = yr[k4];
    float4 xv = xr[k4];
    float4 sc = *(const float4*)&scs[k4 * 4];
    float4 sh = *(const float4*)&shs[k4 * 4];
    float xs[4];
    xs[0] = fmaxf(yv.x * sc.x + sh.x, 0.f) + xv.x;
    xs[1] = fmaxf(yv.y * sc.y + sh.y, 0.f) + xv.y;
    xs[2] = fmaxf(yv.z * sc.z + sh.z, 0.f) + xv.z;
    xs[3] = fmaxf(yv.w * sc.w + sh.w, 0.f) + xv.w;
#pragma unroll
    for (int kk = 0; kk < 4; ++kk)
#pragma unroll
      for (int c = 0; c < 64; ++c) h1[c] += xs[kk] * Ws1[(k4 * 4 + kk) * 64 + c];
  }
  float h2[32];
#pragma unroll
  for (int c = 0; c < 32; ++c) h2[c] = bs2[c];
#pragma unroll
  for (int k = 0; k < 64; ++k) {
    float hv = fmaxf(h1[k], 0.f);
#pragma unroll
    for (int c = 0; c < 32; ++c) h2[c] += hv * Ws2[k * 32 + c];
  }
  float h3[6];
#pragma unroll
  for (int c = 0; c < 6; ++c) h3[c] = bs3[c];
#pragma unroll
  for (int k = 0; k < 32; ++k) {
    float hv = fmaxf(h2[k], 0.f);
#pragma unroll
    for (int c = 0; c < 6; ++c) h3[c] += hv * Ws3[k * 6 + c];
  }
  float* orow = out + (size_t)r * 6;
#pragma unroll
  for (int c = 0; c < 6; ++c) orow[c] = h3[c];
}

extern "C" void kernel_launch(void* const* d_in, const int* in_sizes, int n_in,
                              void* d_out, int out_size, void* d_ws, size_t ws_size,
                              hipStream_t stream) {
  const int* h = (const int*)d_in[0];
  const int* src = (const int*)d_in[1];
  const int* dst = (const int*)d_in[2];
  const float* emb = (const float*)d_in[3];
  const float* W = (const float*)d_in[4];
  const float* b = (const float*)d_in[5];
  const float* gamma = (const float*)d_in[6];
  const float* beta = (const float*)d_in[7];
  const float* W1 = (const float*)d_in[8];
  const float* b1 = (const float*)d_in[9];
  const float* W2 = (const float*)d_in[10];
  const float* b2 = (const float*)d_in[11];
  const float* W3 = (const float*)d_in[12];
  const float* b3 = (const float*)d_in[13];
  float* out = (float*)d_out;

  char* ws = (char*)d_ws;
  size_t off = 0;
  auto alloc = [&](size_t bytes) -> void* {
    void* p = ws + off;
    off += (bytes + 255) & ~(size_t)255;
    return p;
  };
  int* deg_out = (int*)alloc(N_NODES * 4);
  int* deg_in = (int*)alloc(N_NODES * 4);
  float* norm_src = (float*)alloc(N_NODES * 4);
  float* norm_dst = (float*)alloc(N_NODES * 4);
  int* row_ptr = (int*)alloc((N_NODES + 1) * 4);
  int* cursor = (int*)alloc(N_NODES * 4);
  int* csr_src = (int*)alloc((size_t)N_EDGES * 4);
  float* x = (float*)alloc((size_t)N_NODES * HID * 4);
  unsigned short* xb = (unsigned short*)alloc((size_t)N_NODES * HID * 2);
  float* Yb = (float*)alloc((size_t)N_NODES * HID * 4);
  unsigned short* Wh = (unsigned short*)alloc((size_t)N_LAYERS * HID * HID * 2);
  unsigned short* Wl = (unsigned short*)alloc((size_t)N_LAYERS * HID * HID * 2);
  float* sums = (float*)alloc(512);
  float* sumsq = (float*)alloc(512);
  float* scale = (float*)alloc(512);
  float* shift = (float*)alloc(512);
  int* partials = (int*)alloc(SCAN_BLK * 4);
  int* poff = (int*)alloc(SCAN_BLK * 4);

  hipMemsetAsync(deg_out, 0, N_NODES * 4, stream);
  hipMemsetAsync(deg_in, 0, N_NODES * 4, stream);
  k_deg_in<<<(N_EDGES + 255) / 256, 256, 0, stream>>>(dst, deg_in);
  k_scan1<<<SCAN_BLK, 256, 0, stream>>>(deg_in, row_ptr, partials);
  k_scan2<<<1, 128, 0, stream>>>(partials, poff, row_ptr);
  k_scan3<<<SCAN_BLK, 256, 0, stream>>>(row_ptr, poff, cursor);
  k_fill_csr<<<(N_EDGES + 255) / 256, 256, 0, stream>>>(src, dst, cursor, csr_src, deg_out);
  k_norms<<<(N_NODES + 255) / 256, 256, 0, stream>>>(deg_out, deg_in, norm_src, norm_dst);
  k_embed<<<(N_NODES * (HID / 4) + 255) / 256, 256, 0, stream>>>(h, emb, norm_src, x, xb);
  k_wsplit<<<N_LAYERS * 128, 128, 0, stream>>>(W, Wh, Wl);

  for (int l = 0; l < N_LAYERS; ++l) {
    hipMemsetAsync(sums, 0, 1024, stream);  // sums+sumsq contiguous
    k_agg_gemm<<<(N_NODES + 127) / 128, 256, 0, stream>>>(xb, row_ptr, csr_src, norm_dst,
                                                          Wh + (size_t)l * HID * HID, Wl + (size_t)l * HID * HID,
                                                          b + l * HID, Yb, sums, sumsq);
    k_bn_final<<<1, 128, 0, stream>>>(sums, sumsq, gamma + l * HID, beta + l * HID, scale, shift);
    if (l < N_LAYERS - 1) {
      k_bn_apply<<<(N_NODES * (HID / 4) + 255) / 256, 256, 0, stream>>>(Yb, scale, shift, norm_src, x, xb);
    }
  }
  k_mlp_bn_fused<<<(N_NODES + 255) / 256, 256, 0, stream>>>(Yb, x, scale, shift,
                                                            W1, b1, W2, b2, W3, b3, out);
}

// Round 9
// 705.634 us; speedup vs baseline: 1.2775x; 1.2775x over previous
//
#include <hip/hip_runtime.h>

#define N_NODES 100000
#define N_EDGES 1600000
#define HID 128
#define N_LAYERS 4
#define EPSV 1e-5f
#define NBUCK 1024
#define BSHIFT 7      // 128 nodes per bucket
#define CBLK 4096     // edges per scatter block
#define LSTR 40       // LDS row stride in shorts (80B: 16B-aligned, 2-way-max bank conflicts = free)

using f32x4 = __attribute__((ext_vector_type(4))) float;
using s16x8 = __attribute__((ext_vector_type(8))) short;

__device__ __forceinline__ unsigned short f2bf(float f) {
  union { float f; unsigned u; } c{f};
  unsigned u = c.u;
  return (unsigned short)((u + 0x7fffu + ((u >> 16) & 1u)) >> 16);
}
__device__ __forceinline__ float bf2f(unsigned short s) {
  union { unsigned u; float f; } c{(unsigned)s << 16};
  return c.f;
}

// ---------------- Pass A: bucket histogram (LDS) + deg_out atomics ----------------
__global__ __launch_bounds__(256) void k_hist(const int* __restrict__ src, const int* __restrict__ dst,
                                              int* __restrict__ bucket_cnt, int* __restrict__ deg_out) {
  __shared__ int h[NBUCK];
  for (int i = threadIdx.x; i < NBUCK; i += 256) h[i] = 0;
  __syncthreads();
  int per = (N_EDGES + gridDim.x - 1) / gridDim.x;
  int lo = blockIdx.x * per;
  int hi = lo + per; if (hi > N_EDGES) hi = N_EDGES;
  for (int i = lo + threadIdx.x; i < hi; i += 256) {
    atomicAdd(&h[dst[i] >> BSHIFT], 1);
    atomicAdd(&deg_out[src[i]], 1);
  }
  __syncthreads();
  for (int i = threadIdx.x; i < NBUCK; i += 256)
    if (h[i]) atomicAdd(&bucket_cnt[i], h[i]);
}

// ---------------- Pass B: scan 1024 bucket counts; zero bucket_fill ----------------
__global__ __launch_bounds__(256) void k_bscan(const int* __restrict__ cnt, int* __restrict__ base,
                                               int* __restrict__ fill) {
  __shared__ int wsum[4];
  int tid = threadIdx.x;
  int4 v = *(const int4*)(cnt + tid * 4);
  int s4 = v.x + v.y + v.z + v.w;
  int lane = tid & 63, wid = tid >> 6;
  int sc = s4;
#pragma unroll
  for (int off = 1; off < 64; off <<= 1) {
    int u = __shfl_up(sc, off, 64);
    if (lane >= off) sc += u;
  }
  if (lane == 63) wsum[wid] = sc;
  __syncthreads();
  int woff = 0;
#pragma unroll
  for (int w = 0; w < 4; ++w) woff += (w < wid) ? wsum[w] : 0;
  int excl = woff + sc - s4;
  int4 o;
  o.x = excl; o.y = o.x + v.x; o.z = o.y + v.y; o.w = o.z + v.z;
  *(int4*)(base + tid * 4) = o;
  *(int4*)(fill + tid * 4) = make_int4(0, 0, 0, 0);
  if (tid == 255) base[NBUCK] = woff + sc;  // == N_EDGES
}

// ---------------- Pass C: block-local staged scatter (coalesced, no serialization) ----------------
__global__ __launch_bounds__(256) void k_scatter2(const int* __restrict__ src, const int* __restrict__ dst,
                                                  const int* __restrict__ bucket_base, int* __restrict__ bucket_fill,
                                                  int2* __restrict__ pairs) {
  __shared__ int hist[NBUCK];
  __shared__ int loff[NBUCK];
  __shared__ int gbase_s[NBUCK];
  __shared__ int lcur[NBUCK];
  __shared__ int wsum[4];
  __shared__ int2 stage[CBLK];                 // 32 KB
  __shared__ unsigned short sbuck[CBLK];       // 8 KB
  int tid = threadIdx.x;
  int e0 = blockIdx.x * CBLK;
  int e1 = e0 + CBLK; if (e1 > N_EDGES) e1 = N_EDGES;
  int n = e1 - e0;
  for (int i = tid; i < NBUCK; i += 256) hist[i] = 0;
  __syncthreads();
  // load my edges to registers + count
  int2 ev[CBLK / 256];
  int nb[CBLK / 256];
#pragma unroll
  for (int j = 0; j < CBLK / 256; ++j) {
    int idx = e0 + j * 256 + tid;
    nb[j] = -1;
    if (idx < e1) {
      ev[j] = make_int2(src[idx], dst[idx]);
      nb[j] = ev[j].y >> BSHIFT;
      atomicAdd(&hist[nb[j]], 1);
    }
  }
  __syncthreads();
  // scan hist (1024) -> loff
  int4 hv = *(const int4*)(hist + tid * 4);
  int s4 = hv.x + hv.y + hv.z + hv.w;
  int lane = tid & 63, wid = tid >> 6;
  int sc = s4;
#pragma unroll
  for (int off = 1; off < 64; off <<= 1) {
    int u = __shfl_up(sc, off, 64);
    if (lane >= off) sc += u;
  }
  if (lane == 63) wsum[wid] = sc;
  __syncthreads();
  int woff = 0;
#pragma unroll
  for (int w = 0; w < 4; ++w) woff += (w < wid) ? wsum[w] : 0;
  int excl = woff + sc - s4;
  loff[tid * 4 + 0] = excl;
  loff[tid * 4 + 1] = excl + hv.x;
  loff[tid * 4 + 2] = excl + hv.x + hv.y;
  loff[tid * 4 + 3] = excl + hv.x + hv.y + hv.z;
  __syncthreads();
  // reserve global ranges + init local cursors
  for (int b = tid; b < NBUCK; b += 256) {
    int c = hist[b];
    if (c > 0) gbase_s[b] = bucket_base[b] + atomicAdd(&bucket_fill[b], c);
    lcur[b] = loff[b];
  }
  __syncthreads();
  // place into LDS grouped by bucket
#pragma unroll
  for (int j = 0; j < CBLK / 256; ++j) {
    if (nb[j] >= 0) {
      int p = atomicAdd(&lcur[nb[j]], 1);
      stage[p] = ev[j];
      sbuck[p] = (unsigned short)nb[j];
    }
  }
  __syncthreads();
  // coalesced write-out per run
  for (int s = tid; s < n; s += 256) {
    int b = sbuck[s];
    pairs[gbase_s[b] + (s - loff[b])] = stage[s];
  }
}

// ---------------- Pass D: per-bucket exact CSR (no global atomics) ----------------
__global__ __launch_bounds__(256) void k_bucket_csr(const int2* __restrict__ pairs, const int* __restrict__ base,
                                                    int* __restrict__ row_ptr, float* __restrict__ norm_dst,
                                                    int* __restrict__ csr_src) {
  __shared__ int hist[128];
  __shared__ int excl[129];
  __shared__ int curs[128];
  int bk = blockIdx.x;
  int b0 = base[bk], b1 = base[bk + 1];
  int tid = threadIdx.x;
  if (tid < 128) hist[tid] = 0;
  __syncthreads();
  for (int i = b0 + tid; i < b1; i += 256) atomicAdd(&hist[pairs[i].y & 127], 1);
  __syncthreads();
  if (tid < 128) {
    int v = hist[tid];
    int lane = tid & 63;
    int sc = v;
#pragma unroll
    for (int off = 1; off < 64; off <<= 1) {
      int u = __shfl_up(sc, off, 64);
      if (lane >= off) sc += u;
    }
    excl[tid] = sc - v;
    if (lane == 63 && tid < 64) excl[128] = sc;  // wave-0 total
  }
  __syncthreads();
  if (tid >= 64 && tid < 128) excl[tid] += excl[128];
  __syncthreads();
  int gbase = bk << BSHIFT;
  if (tid < 128) {
    int g = gbase + tid;
    if (g < N_NODES) {
      row_ptr[g] = b0 + excl[tid];
      norm_dst[g] = hist[tid] > 0 ? rsqrtf((float)hist[tid]) : 0.f;
    } else if (g == N_NODES) {
      row_ptr[N_NODES] = b0 + excl[tid];
    }
    curs[tid] = excl[tid];
  }
  __syncthreads();
  for (int i = b0 + tid; i < b1; i += 256) {
    int2 p = pairs[i];
    int pos = b0 + atomicAdd(&curs[p.y & 127], 1);
    csr_src[pos] = p.x;
  }
}

// ---------------- norm_src from deg_out ----------------
__global__ __launch_bounds__(256) void k_norms_src(const int* __restrict__ deg_out, float* __restrict__ norm_src) {
  int i = blockIdx.x * 256 + threadIdx.x;
  if (i < N_NODES) {
    int d = deg_out[i];
    norm_src[i] = d > 0 ? rsqrtf((float)d) : 0.f;
  }
}

// ---------------- embedding lookup: writes x (fp32) + xb (bf16, prescaled by norm_src) ----------------
__global__ __launch_bounds__(256) void k_embed(const int* __restrict__ h, const float* __restrict__ emb,
                                               const float* __restrict__ norm_src,
                                               float* __restrict__ x, unsigned short* __restrict__ xb) {
  int i = blockIdx.x * 256 + threadIdx.x;  // over N*32 float4
  const int total = N_NODES * (HID / 4);
  if (i < total) {
    int r = i >> 5, c = i & 31;
    float4 v = ((const float4*)emb)[h[r] * (HID / 4) + c];
    ((float4*)x)[i] = v;
    float ns = norm_src[r];
    uint2 p;
    p.x = (unsigned)f2bf(v.x * ns) | ((unsigned)f2bf(v.y * ns) << 16);
    p.y = (unsigned)f2bf(v.z * ns) | ((unsigned)f2bf(v.w * ns) << 16);
    *(uint2*)(xb + (size_t)i * 4) = p;
  }
}

// ---------------- W split+transpose: Wt[l][col][k] hi/lo bf16 ----------------
__global__ __launch_bounds__(128) void k_wsplit(const float* __restrict__ W, unsigned short* __restrict__ Wh,
                                                unsigned short* __restrict__ Wl) {
  int l = blockIdx.x >> 7, k = blockIdx.x & 127;
  int c = threadIdx.x;
  float w = W[(size_t)l * HID * HID + k * HID + c];
  unsigned short h = f2bf(w);
  Wh[(size_t)l * HID * HID + c * HID + k] = h;
  Wl[(size_t)l * HID * HID + c * HID + k] = f2bf(w - bf2f(h));
}

// ---------------- aggregation (prescaled bf16 gather, fp32 accumulate, hi/lo bf16 output) ----------------
// 16 lanes/node, one 16B load per edge per lane, edge loop unrolled x4 (R4/R7-proven structure).
__global__ __launch_bounds__(256) void k_agg(const unsigned short* __restrict__ xb, const int* __restrict__ row_ptr,
                                             const int* __restrict__ csr_src, const float* __restrict__ norm_dst,
                                             unsigned short* __restrict__ agg_hi, unsigned short* __restrict__ agg_lo) {
  int node = blockIdx.x * 16 + (threadIdx.x >> 4);
  int l16 = threadIdx.x & 15;
  if (node >= N_NODES) return;
  int s0 = row_ptr[node], s1 = row_ptr[node + 1];
  float acc[8];
#pragma unroll
  for (int j = 0; j < 8; ++j) acc[j] = 0.f;
  int i = s0;
  for (; i + 3 < s1; i += 4) {
    int sa = csr_src[i], sb = csr_src[i + 1], sc = csr_src[i + 2], sd = csr_src[i + 3];
    uint4 ua = *(const uint4*)(xb + (size_t)sa * HID + l16 * 8);
    uint4 ub = *(const uint4*)(xb + (size_t)sb * HID + l16 * 8);
    uint4 uc = *(const uint4*)(xb + (size_t)sc * HID + l16 * 8);
    uint4 ud = *(const uint4*)(xb + (size_t)sd * HID + l16 * 8);
    unsigned ue[4][4] = {{ua.x, ua.y, ua.z, ua.w}, {ub.x, ub.y, ub.z, ub.w},
                         {uc.x, uc.y, uc.z, uc.w}, {ud.x, ud.y, ud.z, ud.w}};
#pragma unroll
    for (int e = 0; e < 4; ++e)
#pragma unroll
      for (int q = 0; q < 4; ++q) {
        union { unsigned u; float f; } lo{ue[e][q] << 16}, hi{ue[e][q] & 0xffff0000u};
        acc[q * 2 + 0] += lo.f;
        acc[q * 2 + 1] += hi.f;
      }
  }
  for (; i < s1; ++i) {
    int s = csr_src[i];
    uint4 u = *(const uint4*)(xb + (size_t)s * HID + l16 * 8);
    unsigned uu[4] = {u.x, u.y, u.z, u.w};
#pragma unroll
    for (int q = 0; q < 4; ++q) {
      union { unsigned u; float f; } lo{uu[q] << 16}, hi{uu[q] & 0xffff0000u};
      acc[q * 2 + 0] += lo.f;
      acc[q * 2 + 1] += hi.f;
    }
  }
  float nd = norm_dst[node];
  unsigned short hh[8], ll[8];
#pragma unroll
  for (int j = 0; j < 8; ++j) {
    float v = acc[j] * nd;
    hh[j] = f2bf(v);
    ll[j] = f2bf(v - bf2f(hh[j]));
  }
  uint4 ho, lo4;
  ho.x = (unsigned)hh[0] | ((unsigned)hh[1] << 16); ho.y = (unsigned)hh[2] | ((unsigned)hh[3] << 16);
  ho.z = (unsigned)hh[4] | ((unsigned)hh[5] << 16); ho.w = (unsigned)hh[6] | ((unsigned)hh[7] << 16);
  lo4.x = (unsigned)ll[0] | ((unsigned)ll[1] << 16); lo4.y = (unsigned)ll[2] | ((unsigned)ll[3] << 16);
  lo4.z = (unsigned)ll[4] | ((unsigned)ll[5] << 16); lo4.w = (unsigned)ll[6] | ((unsigned)ll[7] << 16);
  *(uint4*)(agg_hi + (size_t)node * HID + l16 * 8) = ho;
  *(uint4*)(agg_lo + (size_t)node * HID + l16 * 8) = lo4;
}

// ---------------- MFMA GEMM: Y = A@W + b, bf16x3 (fp32-grade), fused BN stats (R7-proven) ----------------
__global__ __launch_bounds__(256, 4) void k_gemm_mfma(const unsigned short* __restrict__ Ah,
                                                      const unsigned short* __restrict__ Al,
                                                      const unsigned short* __restrict__ Bh,
                                                      const unsigned short* __restrict__ Bl,
                                                      const float* __restrict__ bias, float* __restrict__ Y,
                                                      float* __restrict__ sums, float* __restrict__ sumsq) {
  __shared__ unsigned short sAh[128 * LSTR], sAl[128 * LSTR], sBh[128 * LSTR], sBl[128 * LSTR];  // 40960 B
  const int tid = threadIdx.x;
  const int lane = tid & 63, wid = tid >> 6;
  const int l15 = lane & 15, kg = lane >> 4;
  const int row0 = blockIdx.x * 128;

  f32x4 acc[2][8];
#pragma unroll
  for (int mi = 0; mi < 2; ++mi)
#pragma unroll
    for (int ni = 0; ni < 8; ++ni) acc[mi][ni] = (f32x4){0.f, 0.f, 0.f, 0.f};

  for (int kb = 0; kb < 4; ++kb) {
    const int k0 = kb * 32;
#pragma unroll
    for (int it = 0; it < 2; ++it) {
      int idx = tid * 2 + it;
      int r = idx >> 2, q = idx & 3;
      int gr = row0 + r;
      s16x8 vh = {0, 0, 0, 0, 0, 0, 0, 0}, vl = {0, 0, 0, 0, 0, 0, 0, 0};
      if (gr < N_NODES) {
        vh = *(const s16x8*)(Ah + (size_t)gr * HID + k0 + q * 8);
        vl = *(const s16x8*)(Al + (size_t)gr * HID + k0 + q * 8);
      }
      *(s16x8*)&sAh[r * LSTR + q * 8] = vh;
      *(s16x8*)&sAl[r * LSTR + q * 8] = vl;
      *(s16x8*)&sBh[r * LSTR + q * 8] = *(const s16x8*)(Bh + (size_t)r * HID + k0 + q * 8);
      *(s16x8*)&sBl[r * LSTR + q * 8] = *(const s16x8*)(Bl + (size_t)r * HID + k0 + q * 8);
    }
    __syncthreads();
    s16x8 afh[2], afl[2];
#pragma unroll
    for (int mi = 0; mi < 2; ++mi) {
      int ar = wid * 32 + mi * 16 + l15;
      afh[mi] = *(const s16x8*)&sAh[ar * LSTR + kg * 8];
      afl[mi] = *(const s16x8*)&sAl[ar * LSTR + kg * 8];
    }
#pragma unroll
    for (int ni = 0; ni < 8; ++ni) {
      int bc = ni * 16 + l15;
      s16x8 bh = *(const s16x8*)&sBh[bc * LSTR + kg * 8];
      s16x8 bl = *(const s16x8*)&sBl[bc * LSTR + kg * 8];
#pragma unroll
      for (int mi = 0; mi < 2; ++mi) {
        acc[mi][ni] = __builtin_amdgcn_mfma_f32_16x16x32_bf16(afh[mi], bh, acc[mi][ni], 0, 0, 0);
        acc[mi][ni] = __builtin_amdgcn_mfma_f32_16x16x32_bf16(afh[mi], bl, acc[mi][ni], 0, 0, 0);
        acc[mi][ni] = __builtin_amdgcn_mfma_f32_16x16x32_bf16(afl[mi], bh, acc[mi][ni], 0, 0, 0);
      }
    }
    __syncthreads();
  }

  float bv[8], sp[8], qp[8];
#pragma unroll
  for (int ni = 0; ni < 8; ++ni) {
    bv[ni] = bias[ni * 16 + l15];
    sp[ni] = 0.f; qp[ni] = 0.f;
  }
#pragma unroll
  for (int mi = 0; mi < 2; ++mi) {
    int rbase = row0 + wid * 32 + mi * 16 + kg * 4;
#pragma unroll
    for (int reg = 0; reg < 4; ++reg) {
      int r = rbase + reg;
      if (r < N_NODES) {
        float* yr = Y + (size_t)r * HID;
#pragma unroll
        for (int ni = 0; ni < 8; ++ni) {
          float y = acc[mi][ni][reg] + bv[ni];
          yr[ni * 16 + l15] = y;
          sp[ni] += y;
          qp[ni] += y * y;
        }
      }
    }
  }
  __syncthreads();
  float* red_s = (float*)sAh;  // [16][128] = 8KB
  float* red_q = (float*)sBh;
  int slot = wid * 4 + kg;
#pragma unroll
  for (int ni = 0; ni < 8; ++ni) {
    red_s[slot * 128 + ni * 16 + l15] = sp[ni];
    red_q[slot * 128 + ni * 16 + l15] = qp[ni];
  }
  __syncthreads();
  if (tid < 128) {
    float a = 0.f, b2 = 0.f;
#pragma unroll
    for (int s = 0; s < 16; ++s) {
      a += red_s[s * 128 + tid];
      b2 += red_q[s * 128 + tid];
    }
    atomicAdd(&sums[tid], a);
    atomicAdd(&sumsq[tid], b2);
  }
}

// ---------------- BN finalize ----------------
__global__ __launch_bounds__(128) void k_bn_final(const float* __restrict__ sums, const float* __restrict__ sumsq,
                                                  const float* __restrict__ gamma, const float* __restrict__ beta,
                                                  float* __restrict__ scale, float* __restrict__ shift) {
  int d = threadIdx.x;
  float mu = sums[d] / (float)N_NODES;
  float var = sumsq[d] / (float)N_NODES - mu * mu;
  float sc = gamma[d] * rsqrtf(var + EPSV);
  scale[d] = sc;
  shift[d] = beta[d] - mu * sc;
}

// ---------------- BN apply + relu + residual; writes x (fp32) + xb (bf16, prescaled) ----------------
__global__ __launch_bounds__(256) void k_bn_apply(const float* __restrict__ Y, const float* __restrict__ scale,
                                                  const float* __restrict__ shift, const float* __restrict__ norm_src,
                                                  float* __restrict__ x, unsigned short* __restrict__ xb) {
  int i = blockIdx.x * 256 + threadIdx.x;
  const int total = N_NODES * (HID / 4);
  if (i >= total) return;
  int c4 = i & 31, r = i >> 5;
  float4 y = ((const float4*)Y)[i];
  float4 sc = ((const float4*)scale)[c4];
  float4 sh = ((const float4*)shift)[c4];
  float4 xv = ((const float4*)x)[i];
  float4 o;
  o.x = fmaxf(y.x * sc.x + sh.x, 0.f) + xv.x;
  o.y = fmaxf(y.y * sc.y + sh.y, 0.f) + xv.y;
  o.z = fmaxf(y.z * sc.z + sh.z, 0.f) + xv.z;
  o.w = fmaxf(y.w * sc.w + sh.w, 0.f) + xv.w;
  ((float4*)x)[i] = o;
  float ns = norm_src[r];
  uint2 p;
  p.x = (unsigned)f2bf(o.x * ns) | ((unsigned)f2bf(o.y * ns) << 16);
  p.y = (unsigned)f2bf(o.z * ns) | ((unsigned)f2bf(o.w * ns) << 16);
  *(uint2*)(xb + (size_t)i * 4) = p;
}

// ---------------- fused layer-4 BN + MLP readout ----------------
__global__ __launch_bounds__(256) void k_mlp_bn_fused(const float* __restrict__ Yb, const float* __restrict__ Xres,
                                                      const float* __restrict__ scale, const float* __restrict__ shift,
                                                      const float* __restrict__ W1, const float* __restrict__ b1,
                                                      const float* __restrict__ W2, const float* __restrict__ b2,
                                                      const float* __restrict__ W3, const float* __restrict__ b3,
                                                      float* __restrict__ out) {
  __shared__ float Ws1[128 * 64];
  __shared__ float Ws2[64 * 32];
  __shared__ float Ws3[32 * 6];
  __shared__ float bs1[64], bs2[32], bs3[6];
  __shared__ float scs[128], shs[128];
  for (int i = threadIdx.x; i < 128 * 64; i += 256) Ws1[i] = W1[i];
  for (int i = threadIdx.x; i < 64 * 32; i += 256) Ws2[i] = W2[i];
  for (int i = threadIdx.x; i < 32 * 6; i += 256) Ws3[i] = W3[i];
  if (threadIdx.x < 64) bs1[threadIdx.x] = b1[threadIdx.x];
  else if (threadIdx.x < 96) bs2[threadIdx.x - 64] = b2[threadIdx.x - 64];
  else if (threadIdx.x < 102) bs3[threadIdx.x - 96] = b3[threadIdx.x - 96];
  if (threadIdx.x < 128) { scs[threadIdx.x] = scale[threadIdx.x]; shs[threadIdx.x] = shift[threadIdx.x]; }
  __syncthreads();
  int r = blockIdx.x * 256 + threadIdx.x;
  if (r >= N_NODES) return;
  const float4* yr = (const float4*)(Yb + (size_t)r * 128);
  const float4* xr = (const float4*)(Xres + (size_t)r * 128);
  float h1[64];
#pragma unroll
  for (int c = 0; c < 64; ++c) h1[c] = bs1[c];
  for (int k4 = 0; k4 < 32; ++k4) {
    float4 yv = yr[k4];
    float4 xv = xr[k4];
    float4 sc = *(const float4*)&scs[k4 * 4];
    float4 sh = *(const float4*)&shs[k4 * 4];
    float xs[4];
    xs[0] = fmaxf(yv.x * sc.x + sh.x, 0.f) + xv.x;
    xs[1] = fmaxf(yv.y * sc.y + sh.y, 0.f) + xv.y;
    xs[2] = fmaxf(yv.z * sc.z + sh.z, 0.f) + xv.z;
    xs[3] = fmaxf(yv.w * sc.w + sh.w, 0.f) + xv.w;
#pragma unroll
    for (int kk = 0; kk < 4; ++kk)
#pragma unroll
      for (int c = 0; c < 64; ++c) h1[c] += xs[kk] * Ws1[(k4 * 4 + kk) * 64 + c];
  }
  float h2[32];
#pragma unroll
  for (int c = 0; c < 32; ++c) h2[c] = bs2[c];
#pragma unroll
  for (int k = 0; k < 64; ++k) {
    float hv = fmaxf(h1[k], 0.f);
#pragma unroll
    for (int c = 0; c < 32; ++c) h2[c] += hv * Ws2[k * 32 + c];
  }
  float h3[6];
#pragma unroll
  for (int c = 0; c < 6; ++c) h3[c] = bs3[c];
#pragma unroll
  for (int k = 0; k < 32; ++k) {
    float hv = fmaxf(h2[k], 0.f);
#pragma unroll
    for (int c = 0; c < 6; ++c) h3[c] += hv * Ws3[k * 6 + c];
  }
  float* orow = out + (size_t)r * 6;
#pragma unroll
  for (int c = 0; c < 6; ++c) orow[c] = h3[c];
}

extern "C" void kernel_launch(void* const* d_in, const int* in_sizes, int n_in,
                              void* d_out, int out_size, void* d_ws, size_t ws_size,
                              hipStream_t stream) {
  const int* h = (const int*)d_in[0];
  const int* src = (const int*)d_in[1];
  const int* dst = (const int*)d_in[2];
  const float* emb = (const float*)d_in[3];
  const float* W = (const float*)d_in[4];
  const float* b = (const float*)d_in[5];
  const float* gamma = (const float*)d_in[6];
  const float* beta = (const float*)d_in[7];
  const float* W1 = (const float*)d_in[8];
  const float* b1 = (const float*)d_in[9];
  const float* W2 = (const float*)d_in[10];
  const float* b2 = (const float*)d_in[11];
  const float* W3 = (const float*)d_in[12];
  const float* b3 = (const float*)d_in[13];
  float* out = (float*)d_out;

  char* ws = (char*)d_ws;
  size_t off = 0;
  auto alloc = [&](size_t bytes) -> void* {
    void* p = ws + off;
    off += (bytes + 255) & ~(size_t)255;
    return p;
  };
  int* deg_out = (int*)alloc(N_NODES * 4);
  float* norm_src = (float*)alloc(N_NODES * 4);
  float* norm_dst = (float*)alloc(N_NODES * 4);
  int* row_ptr = (int*)alloc((N_NODES + 1) * 4);
  int* csr_src = (int*)alloc((size_t)N_EDGES * 4);
  int* bucket_cnt = (int*)alloc(NBUCK * 4);
  int* bucket_base = (int*)alloc((NBUCK + 1) * 4);
  int* bucket_fill = (int*)alloc(NBUCK * 4);
  float* x = (float*)alloc((size_t)N_NODES * HID * 4);
  unsigned short* xb = (unsigned short*)alloc((size_t)N_NODES * HID * 2);
  unsigned short* agg_hi = (unsigned short*)alloc((size_t)N_NODES * HID * 2);
  unsigned short* agg_lo = (unsigned short*)alloc((size_t)N_NODES * HID * 2);
  float* Yb = (float*)alloc((size_t)N_NODES * HID * 4);
  unsigned short* Wh = (unsigned short*)alloc((size_t)N_LAYERS * HID * HID * 2);
  unsigned short* Wl = (unsigned short*)alloc((size_t)N_LAYERS * HID * HID * 2);
  float* sums = (float*)alloc(512);
  float* sumsq = (float*)alloc(512);
  float* scale = (float*)alloc(512);
  float* shift = (float*)alloc(512);
  int2* pairs = (int2*)Yb;  // overlay: pairs (12.8MB) dead before Yb first written (layer-1 gemm)

  hipMemsetAsync(deg_out, 0, N_NODES * 4, stream);
  hipMemsetAsync(bucket_cnt, 0, NBUCK * 4, stream);
  k_hist<<<256, 256, 0, stream>>>(src, dst, bucket_cnt, deg_out);
  k_bscan<<<1, 256, 0, stream>>>(bucket_cnt, bucket_base, bucket_fill);
  k_scatter2<<<(N_EDGES + CBLK - 1) / CBLK, 256, 0, stream>>>(src, dst, bucket_base, bucket_fill, pairs);
  k_bucket_csr<<<NBUCK, 256, 0, stream>>>(pairs, bucket_base, row_ptr, norm_dst, csr_src);
  k_norms_src<<<(N_NODES + 255) / 256, 256, 0, stream>>>(deg_out, norm_src);
  k_embed<<<(N_NODES * (HID / 4) + 255) / 256, 256, 0, stream>>>(h, emb, norm_src, x, xb);
  k_wsplit<<<N_LAYERS * 128, 128, 0, stream>>>(W, Wh, Wl);

  for (int l = 0; l < N_LAYERS; ++l) {
    k_agg<<<(N_NODES + 15) / 16, 256, 0, stream>>>(xb, row_ptr, csr_src, norm_dst, agg_hi, agg_lo);
    hipMemsetAsync(sums, 0, 1024, stream);  // sums+sumsq contiguous
    k_gemm_mfma<<<(N_NODES + 127) / 128, 256, 0, stream>>>(agg_hi, agg_lo,
                                                           Wh + (size_t)l * HID * HID, Wl + (size_t)l * HID * HID,
                                                           b + l * HID, Yb, sums, sumsq);
    k_bn_final<<<1, 128, 0, stream>>>(sums, sumsq, gamma + l * HID, beta + l * HID, scale, shift);
    if (l < N_LAYERS - 1) {
      k_bn_apply<<<(N_NODES * (HID / 4) + 255) / 256, 256, 0, stream>>>(Yb, scale, shift, norm_src, x, xb);
    }
  }
  k_mlp_bn_fused<<<(N_NODES + 255) / 256, 256, 0, stream>>>(Yb, x, scale, shift,
                                                            W1, b1, W2, b2, W3, b3, out);
}